// Round 6
// baseline (420.948 us; speedup 1.0000x reference)
//
#include <hip/hip_runtime.h>
#include <type_traits>

namespace {
constexpr int HH = 512, WW = 512;
constexpr int KS = 11, PADR = 5;
constexpr int BH = 32;            // output rows per block (band)
constexpr int SR = 4;             // rows per slab
constexpr int NSLAB = BH / SR;    // 8
constexpr int WIN = SR + 2*PADR;  // 14-row sliding window
constexpr int PITCH = 528;        // 8 pad | 512 cols | 8 pad (16B-aligned)
constexpr int NT = 512;
constexpr float SSIM_C1 = 1.0e-4f;
constexpr float SSIM_C2 = 9.0e-4f;
}

// Block = full-width 512x32 band, 768 blocks = exactly 3 per CU (no tail).
// R5 post-mortem: sliding-window algorithm is right (each pixel loaded and
// squared ONCE vs 11-22x in R4), but v2f windows (56 persistent VGPRs) +
// cap-170 spilled ~700 MB to scratch. Fix: 512 threads x 1 scalar column
// -> window state 28 VGPRs, peak live ~95; launch_bounds(512,4) caps at 128
// (cap > demand; R2/R5 both violated that). 2 blocks/CU = 16 waves = 50%.
// Per slab: phase-1 vertical 11-tap sums of {x,y,xx,yy,xy} -> LDS; shift
// window + issue tail loads (retire under phase 2); phase-2 horizontal
// 11-tap from aligned ds_read_b128 + SSIM + float4 store.
__global__ __launch_bounds__(NT, 4) void ssim_fused(
    const float* __restrict__ x, const float* __restrict__ y,
    const float* __restrict__ kern, float* __restrict__ out)
{
    __shared__ __align__(16) float vb[5][SR][PITCH];   // 42240 B

    const int bid = blockIdx.x;
    const int plane = bid >> 4;          // 48 planes
    const int band = bid & 15;           // 16 bands
    const int R0 = band << 5;

    const float* __restrict__ xp = x + (size_t)plane * (HH * WW);
    const float* __restrict__ yp = y + (size_t)plane * (HH * WW);
    float* __restrict__ op = out + (size_t)plane * (HH * WW);

    // 1D gaussian from 2D kernel (exact for outer products)
    float wt[KS];
    {
        const float inv = rsqrtf(kern[5 * KS + 5]);
#pragma unroll
        for (int i = 0; i < KS; ++i) wt[i] = kern[5 * KS + i] * inv;
    }

    const int t = threadIdx.x;           // owned column 0..511
    const int q  = t & 127;             // phase-2 col quad (cols 4q..4q+3)
    const int r2 = t >> 7;              // phase-2 slab row 0..3

    // zero horizontal pad columns (idx 0..7 = cols -8..-1, 520..527) once;
    // first phase-1 barrier makes them visible before any phase-2 read.
    if (t < 5 * SR * 16) {
        const int st = t >> 6;
        const int rem = t & 63;
        const int r = rem >> 4;
        const int j = rem & 15;
        vb[st][r][(j < 8) ? j : (512 + j)] = 0.f;
    }

    auto body = [&](auto edge_tag) {
        constexpr bool EDGE = decltype(edge_tag)::value;

        auto ld = [&](int row, float& ax, float& ay) {
            if (!EDGE || (unsigned)row < (unsigned)HH) {  // row is wave-uniform
                ax = xp[row * WW + t];
                ay = yp[row * WW + t];
            } else { ax = 0.f; ay = 0.f; }
        };

        // prime the sliding windows with input rows R0-5 .. R0+8
        float xw[WIN], yw[WIN];
#pragma unroll
        for (int i = 0; i < WIN; ++i) ld(R0 - PADR + i, xw[i], yw[i]);

        for (int s = 0; s < NSLAB; ++s) {
            // ---- phase 1: vertical 11-tap sums for SR rows, own column ----
#pragma unroll
            for (int j = 0; j < SR; ++j) {        // ux
                float a = wt[0] * xw[j];
#pragma unroll
                for (int k = 1; k < KS; ++k) a += wt[k] * xw[j + k];
                vb[0][j][8 + t] = a;
            }
#pragma unroll
            for (int j = 0; j < SR; ++j) {        // uy
                float a = wt[0] * yw[j];
#pragma unroll
                for (int k = 1; k < KS; ++k) a += wt[k] * yw[j + k];
                vb[1][j][8 + t] = a;
            }
            {   // uxx: squares computed once per slab
                float tmp[WIN];
#pragma unroll
                for (int i = 0; i < WIN; ++i) tmp[i] = xw[i] * xw[i];
#pragma unroll
                for (int j = 0; j < SR; ++j) {
                    float a = wt[0] * tmp[j];
#pragma unroll
                    for (int k = 1; k < KS; ++k) a += wt[k] * tmp[j + k];
                    vb[2][j][8 + t] = a;
                }
            }
            {   // uyy
                float tmp[WIN];
#pragma unroll
                for (int i = 0; i < WIN; ++i) tmp[i] = yw[i] * yw[i];
#pragma unroll
                for (int j = 0; j < SR; ++j) {
                    float a = wt[0] * tmp[j];
#pragma unroll
                    for (int k = 1; k < KS; ++k) a += wt[k] * tmp[j + k];
                    vb[3][j][8 + t] = a;
                }
            }
            {   // uxy
                float tmp[WIN];
#pragma unroll
                for (int i = 0; i < WIN; ++i) tmp[i] = xw[i] * yw[i];
#pragma unroll
                for (int j = 0; j < SR; ++j) {
                    float a = wt[0] * tmp[j];
#pragma unroll
                    for (int k = 1; k < KS; ++k) a += wt[k] * tmp[j + k];
                    vb[4][j][8 + t] = a;
                }
            }

            // shift window; issue next slab's 4-row loads into the tail now
            // so they retire under phase-2 compute (no extra arrays/regs)
            if (s + 1 < NSLAB) {
#pragma unroll
                for (int i = 0; i < WIN - SR; ++i) {
                    xw[i] = xw[i + SR];
                    yw[i] = yw[i + SR];
                }
#pragma unroll
                for (int j = 0; j < SR; ++j)
                    ld(R0 - PADR + WIN + s * SR + j,
                       xw[WIN - SR + j], yw[WIN - SR + j]);
            }
            __syncthreads();

            // ---- phase 2: horizontal 11-tap + SSIM, one quad-row/thread --
            float u[5][4];
#pragma unroll
            for (int st = 0; st < 5; ++st) {
                float wnd[17];
#pragma unroll
                for (int ch = 0; ch < 4; ++ch) {
                    const float4 v = *(const float4*)&vb[st][r2][4 * q + 4 * ch];
                    wnd[4 * ch + 0] = v.x;
                    wnd[4 * ch + 1] = v.y;
                    wnd[4 * ch + 2] = v.z;
                    wnd[4 * ch + 3] = v.w;
                }
                wnd[16] = vb[st][r2][4 * q + 16];
                // output col 4q+d, tap k -> padded idx 4q + (3+d+k)
#pragma unroll
                for (int d = 0; d < 4; ++d) {
                    float a = wt[0] * wnd[d + 3];
#pragma unroll
                    for (int k = 1; k < KS; ++k) a += wt[k] * wnd[d + 3 + k];
                    u[st][d] = a;
                }
            }
            float4 o;
#pragma unroll
            for (int d = 0; d < 4; ++d) {
                const float ux = u[0][d], uy = u[1][d];
                const float uxx = u[2][d], uyy = u[3][d], uxy = u[4][d];
                const float vx  = uxx - ux * ux;
                const float vy  = uyy - uy * uy;
                const float vxy = uxy - ux * uy;
                const float a1 = 2.f * ux * uy + SSIM_C1;
                const float a2 = 2.f * vxy + SSIM_C2;
                const float b1 = ux * ux + uy * uy + SSIM_C1;
                const float b2 = vx + vy + SSIM_C2;
                (&o.x)[d] = (a1 * a2) * __builtin_amdgcn_rcpf(b1 * b2);
            }
            *(float4*)&op[(size_t)(R0 + s * SR + r2) * WW + 4 * q] = o;
            __syncthreads();   // vb reused by next slab
        }
    };

    // bands 1..14 never touch rows <0 or >=512 -> unguarded loads
    if (band >= 1 && band <= 14) body(std::false_type{});
    else                         body(std::true_type{});
}

extern "C" void kernel_launch(void* const* d_in, const int* in_sizes, int n_in,
                              void* d_out, int out_size, void* d_ws, size_t ws_size,
                              hipStream_t stream) {
    const float* x    = (const float*)d_in[0];
    const float* y    = (const float*)d_in[1];
    const float* kern = (const float*)d_in[2];
    float* out = (float*)d_out;

    const int nplanes = in_sizes[0] / (HH * WW);      // 48
    const int nblocks = nplanes * (HH / BH);          // 768

    ssim_fused<<<dim3(nblocks), dim3(NT), 0, stream>>>(x, y, kern, out);
}